// Round 2
// baseline (526.814 us; speedup 1.0000x reference)
//
#include <hip/hip_runtime.h>
#include <hip/hip_cooperative_groups.h>

namespace cg = cooperative_groups;

// Fixed shapes from the reference: B=64, C=64, H=96, W=96 (Q10 fixed point).
#define B_   64
#define C_   64
#define HW_  9216                      // 96*96
#define NSLAB (B_ * C_)                // 4096 contiguous [b][c] slabs of HW_ ints
#define M_   ((long long)B_ * HW_)     // 589824 elements per channel
#define FX_ONE_SQRT 32
#define SLABS_PER_BLK 4
#define GRID_ (NSLAB / SLABS_PER_BLK)  // 1024 blocks * 4 waves = 4096 waves
                                       // = 4 blocks/CU -> co-residency safe for
                                       // cooperative launch at any VGPR <= 128

typedef int v4i __attribute__((ext_vector_type(4)));

// Single persistent cooperative kernel:
//   phase 1: per-slab sum / sum-of-squares (pure 32-bit per-thread accum:
//            36 elems/thread/slab, sum < 2^17, sumsq 1.51e8 < 2^31)
//   grid sync
//   phase 2: waves 0..3 compute the 4 channels' params (mean round-to-nearest,
//            exact centered var, exact bit-serial isqrt — all |diff|<=1 vs the
//            reference's floor+Bernoulli, threshold 36.48), then normalize with
//            ONE f32 FMA per element:
//              y = round_ne(x*s + t), s = fl32(gamma/den), t = fl32(beta - mean*s)
//            (f32 error < 2e-3 << 0.5 for |x-mean|<=2048 -> result stays in the
//            reference's {floor, floor+1} candidate set).
// Fusion eliminates one kernel launch + inter-dispatch gap; x is L3-resident
// across the grid sync so phase 2 reads hit L3; y uses NT stores to keep x
// from being evicted.
__global__ __launch_bounds__(256, 4) void k_fused(
        const int* __restrict__ x, int* __restrict__ y,
        long long* __restrict__ part,
        const int* __restrict__ gammap, const int* __restrict__ betap,
        const int* __restrict__ mov_mean, const int* __restrict__ mov_std,
        const int* __restrict__ is_t_p) {
    const int s0 = blockIdx.x * SLABS_PER_BLK;
    __shared__ long long ss[4], sq[4];

    // ---------------- phase 1: reduce 4 slabs ----------------
    for (int t = 0; t < SLABS_PER_BLK; ++t) {
        const int slab = s0 + t;
        const v4i* p = (const v4i*)(x + (size_t)slab * HW_);
        unsigned tsum = 0, tsq = 0;
#pragma unroll
        for (int i = 0; i < HW_ / 4 / 256; ++i) {         // 9 int4 per thread
            v4i v = p[threadIdx.x + i * 256];
            tsum += (unsigned)(v.x + v.y + v.z + v.w);
            tsq  += (unsigned)(v.x * v.x) + (unsigned)(v.y * v.y)
                  + (unsigned)(v.z * v.z) + (unsigned)(v.w * v.w);
        }
        long long s = tsum, q = tsq;
#pragma unroll
        for (int off = 32; off > 0; off >>= 1) {          // wave64 reduce
            s += __shfl_down(s, off, 64);
            q += __shfl_down(q, off, 64);
        }
        const int wave = threadIdx.x >> 6, lane = threadIdx.x & 63;
        if (lane == 0) { ss[wave] = s; sq[wave] = q; }
        __syncthreads();
        if (threadIdx.x == 0) {
            part[2 * slab]     = ss[0] + ss[1] + ss[2] + ss[3];
            part[2 * slab + 1] = sq[0] + sq[1] + sq[2] + sq[3];
        }
        __syncthreads();                                  // ss/sq reused next t
    }

    __threadfence();                                      // cross-XCD visibility
    cg::this_grid().sync();

    // ---------------- phase 2: params (waves 0..3) + normalize ----------------
    __shared__ float shs[SLABS_PER_BLK], sht[SLABS_PER_BLK];
    const int wave = threadIdx.x >> 6, lane = threadIdx.x & 63;
    {
        const int c = (s0 + wave) & (C_ - 1);             // channel of slab s0+wave
        long long s = part[2 * (lane * C_ + c)];          // lane = batch index b
        long long q = part[2 * (lane * C_ + c) + 1];
#pragma unroll
        for (int off = 32; off > 0; off >>= 1) {
            s += __shfl_down(s, off, 64);
            q += __shfl_down(q, off, 64);
        }
        if (lane == 0) {
            int mean, den;
            if (is_t_p[0]) {
                mean = (int)((s + M_ / 2) / M_);
                long long sc = q - 2LL * mean * s + M_ * (long long)mean * mean;
                long long d2 = M_ * 1024LL;
                long long var = (sc + d2 / 2) / d2;
                long long v = var + 1;                    // + EPS_FX
                long long r = 0, a = 1LL << 30;           // bit-serial isqrt
                while (a) {
                    if (r + a <= v) { v -= r + a; r = (r >> 1) + a; }
                    else            { r >>= 1; }
                    a >>= 2;
                }
                den = (int)(r * FX_ONE_SQRT);
            } else {
                mean = mov_mean[c];
                den  = mov_std[c];
            }
            const float sf = (float)((double)gammap[c] / (double)den);
            shs[wave] = sf;
            // exact in double: mean*(double)sf has <= 35 significant bits
            sht[wave] = (float)((double)betap[c] - (double)mean * (double)sf);
        }
    }
    __syncthreads();

    for (int t = 0; t < SLABS_PER_BLK; ++t) {
        const int slab = s0 + t;
        const float scf = shs[t], tcf = sht[t];
        const v4i* xp = (const v4i*)(x + (size_t)slab * HW_);
        v4i*       yp = (v4i*)(y + (size_t)slab * HW_);
#pragma unroll
        for (int i = 0; i < HW_ / 4 / 256; ++i) {
            v4i v = xp[threadIdx.x + i * 256];
            v4i o;
#pragma unroll
            for (int j = 0; j < 4; ++j)
                o[j] = __float2int_rn(fmaf((float)v[j], scf, tcf));
            // Non-temporal: keep y out of L3 so x stays resident for the reads.
            __builtin_nontemporal_store(o, &yp[threadIdx.x + i * 256]);
        }
    }
}

extern "C" void kernel_launch(void* const* d_in, const int* in_sizes, int n_in,
                              void* d_out, int out_size, void* d_ws, size_t ws_size,
                              hipStream_t stream) {
    const int* x        = (const int*)d_in[0];
    const int* gamma    = (const int*)d_in[1];
    const int* beta     = (const int*)d_in[2];
    const int* mov_mean = (const int*)d_in[3];
    const int* mov_std  = (const int*)d_in[4];
    const int* is_t     = (const int*)d_in[5];
    int* y = (int*)d_out;

    long long* part = (long long*)d_ws;                   // 4096*2 int64 = 64 KB

    void* args[] = {(void*)&x, (void*)&y, (void*)&part, (void*)&gamma,
                    (void*)&beta, (void*)&mov_mean, (void*)&mov_std,
                    (void*)&is_t};
    hipLaunchCooperativeKernel((void*)k_fused, dim3(GRID_), dim3(256),
                               args, 0, stream);
}

// Round 3
// 283.276 us; speedup vs baseline: 1.8597x; 1.8597x over previous
//
#include <hip/hip_runtime.h>

// Fixed shapes from the reference: B=64, C=64, H=96, W=96 (Q10 fixed point).
#define B_   64
#define C_   64
#define HW_  9216                      // 96*96
#define NSLAB (B_ * C_)                // 4096 contiguous [b][c] slabs of HW_ ints
#define M_   ((long long)B_ * HW_)     // 589824 elements per channel
#define FX_ONE_SQRT 32

typedef int v4i __attribute__((ext_vector_type(4)));

// ---------------- Kernel 1: per-slab sum / sum-of-squares ----------------
// 2 slabs per block, interleaved independent accumulator chains: 18 int4
// loads/thread in flight (vs 9) to cover ~900-cycle cold-HBM latency.
// Round-2 evidence: the fused kernel ran at 924 GB/s with minimal traffic ->
// the read side is latency/MLP-bound, not traffic-bound.
// 32-bit per-thread accumulation is safe: 36 elems/thread/slab,
// max sum 36*2047 < 2^17, max sumsq 36*2047^2 = 1.51e8 < 2^31.
__global__ __launch_bounds__(256) void k_reduce(const int* __restrict__ x,
                                                long long* __restrict__ part) {
    const int slab0 = blockIdx.x * 2;
    const v4i* p0 = (const v4i*)(x + (size_t)slab0 * HW_);
    const v4i* p1 = p0 + (HW_ / 4);
    unsigned ts0 = 0, tq0 = 0, ts1 = 0, tq1 = 0;
#pragma unroll
    for (int i = 0; i < HW_ / 4 / 256; ++i) {             // 9 iters, 2 loads each
        v4i a = p0[threadIdx.x + i * 256];
        v4i b = p1[threadIdx.x + i * 256];
        ts0 += (unsigned)(a.x + a.y + a.z + a.w);
        tq0 += (unsigned)(a.x * a.x) + (unsigned)(a.y * a.y)
             + (unsigned)(a.z * a.z) + (unsigned)(a.w * a.w);
        ts1 += (unsigned)(b.x + b.y + b.z + b.w);
        tq1 += (unsigned)(b.x * b.x) + (unsigned)(b.y * b.y)
             + (unsigned)(b.z * b.z) + (unsigned)(b.w * b.w);
    }
    long long s0 = ts0, q0 = tq0, s1 = ts1, q1 = tq1;
#pragma unroll
    for (int off = 32; off > 0; off >>= 1) {              // wave64 reduce
        s0 += __shfl_down(s0, off, 64);
        q0 += __shfl_down(q0, off, 64);
        s1 += __shfl_down(s1, off, 64);
        q1 += __shfl_down(q1, off, 64);
    }
    __shared__ long long sm_s[4][2], sm_q[4][2];
    const int wave = threadIdx.x >> 6, lane = threadIdx.x & 63;
    if (lane == 0) {
        sm_s[wave][0] = s0; sm_q[wave][0] = q0;
        sm_s[wave][1] = s1; sm_q[wave][1] = q1;
    }
    __syncthreads();
    if (threadIdx.x == 0) {
        part[2 * slab0]     = sm_s[0][0] + sm_s[1][0] + sm_s[2][0] + sm_s[3][0];
        part[2 * slab0 + 1] = sm_q[0][0] + sm_q[1][0] + sm_q[2][0] + sm_q[3][0];
        part[2 * slab0 + 2] = sm_s[0][1] + sm_s[1][1] + sm_s[2][1] + sm_s[3][1];
        part[2 * slab0 + 3] = sm_q[0][1] + sm_q[1][1] + sm_q[2][1] + sm_q[3][1];
    }
}

// ---------------- Kernel 2: fused params + normalize ----------------
// (unchanged from the 283 us version)
// Each block redundantly computes its own channel's params from the 64
// per-batch partials (deterministic -> all 64 blocks of a channel agree):
//  - mean: round-to-nearest (ref: floor + Bernoulli; |diff| <= 1)
//  - var:  round-to-nearest of exact centered sumsq / (1024*M)
//  - isqrt: exact bit-serial (ref's internal fx_div(r,2) always has mod==0)
// Final fx_div as ONE f32 FMA per element:
//   y = round_ne(x*s + t), s = fl32(gamma/den), t = fl32(beta - mean*(double)s)
// f32 error < 2e-3 << 0.5 -> result stays in the reference's {floor, floor+1}
// candidate set (stochastic-rounding tolerance threshold is 36.48).
__global__ __launch_bounds__(256) void k_norm(const int* __restrict__ x,
                                              int* __restrict__ y,
                                              const long long* __restrict__ part,
                                              const int* __restrict__ gammap,
                                              const int* __restrict__ betap,
                                              const int* __restrict__ mov_mean,
                                              const int* __restrict__ mov_std,
                                              const int* __restrict__ is_t_p) {
    __shared__ float sh_s, sh_t;
    const int slab = blockIdx.x;
    const int c = slab & (C_ - 1);

    if (threadIdx.x < 64) {                               // wave 0: channel params
        const int b = threadIdx.x;
        long long s = part[2 * (b * C_ + c)];
        long long q = part[2 * (b * C_ + c) + 1];
#pragma unroll
        for (int off = 32; off > 0; off >>= 1) {
            s += __shfl_down(s, off, 64);
            q += __shfl_down(q, off, 64);
        }
        if (b == 0) {
            int mean, den;
            if (is_t_p[0]) {
                mean = (int)((s + M_ / 2) / M_);
                long long sc = q - 2LL * mean * s + M_ * (long long)mean * mean;
                long long d2 = M_ * 1024LL;
                long long var = (sc + d2 / 2) / d2;
                long long v = var + 1;                    // + EPS_FX
                long long r = 0, a = 1LL << 30;           // bit-serial isqrt
                while (a) {
                    if (r + a <= v) { v -= r + a; r = (r >> 1) + a; }
                    else            { r >>= 1; }
                    a >>= 2;
                }
                den = (int)(r * FX_ONE_SQRT);
            } else {
                mean = mov_mean[c];
                den  = mov_std[c];
            }
            const float sf = (float)((double)gammap[c] / (double)den);
            sh_s = sf;
            // exact in double: mean*(double)sf has <= 35 significant bits
            sh_t = (float)((double)betap[c] - (double)mean * (double)sf);
        }
    }
    __syncthreads();
    const float sc = sh_s, tc = sh_t;

    const v4i* xp = (const v4i*)(x + (size_t)slab * HW_);
    v4i*       yp = (v4i*)(y + (size_t)slab * HW_);
#pragma unroll
    for (int i = 0; i < HW_ / 4 / 256; ++i) {
        v4i v = xp[threadIdx.x + i * 256];
        v4i o;
#pragma unroll
        for (int j = 0; j < 4; ++j)
            o[j] = __float2int_rn(fmaf((float)v[j], sc, tc));
        // Non-temporal: keep y out of L3 so x stays resident for the reads.
        __builtin_nontemporal_store(o, &yp[threadIdx.x + i * 256]);
    }
}

extern "C" void kernel_launch(void* const* d_in, const int* in_sizes, int n_in,
                              void* d_out, int out_size, void* d_ws, size_t ws_size,
                              hipStream_t stream) {
    const int* x        = (const int*)d_in[0];
    const int* gamma    = (const int*)d_in[1];
    const int* beta     = (const int*)d_in[2];
    const int* mov_mean = (const int*)d_in[3];
    const int* mov_std  = (const int*)d_in[4];
    const int* is_t     = (const int*)d_in[5];
    int* y = (int*)d_out;

    long long* part = (long long*)d_ws;                   // 4096*2 int64 = 64 KB

    k_reduce<<<NSLAB / 2, 256, 0, stream>>>(x, part);
    k_norm<<<NSLAB, 256, 0, stream>>>(x, y, part, gamma, beta,
                                      mov_mean, mov_std, is_t);
}